// Round 5
// baseline (271.422 us; speedup 1.0000x reference)
//
#include <hip/hip_runtime.h>
#include <cmath>

// d_ws layout (floats):
//   [0      .. 1024)   ee[k] = numpy-pairwise sum of E[k][:]^2  (f32)
//   [1024   .. 2048)   counts[k]
//   [2048   .. 67584)  dw[k][d]  (1024*64)
//   [67584]            mse accumulator
//
// d_out layout (floats, concatenated in reference return order):
//   [0        .. 4194304)  quant_out (16,64,64,64)
//   [4194304]              loss
//   [4194305  .. 4259841)  idx (as float)
//   [4259841  .. 4325377)  new_embedding (1024,64)
//   [4325377  .. 4326401)  new_cs (1024)
//   [4326401  .. 4391937)  new_ema_w (1024,64)

__global__ __launch_bounds__(256) void vq_init_kernel(const float* __restrict__ E,
                                                      float* __restrict__ ws) {
    #pragma clang fp contract(off)
    int g = blockIdx.x * 256 + threadIdx.x;        // 256 blocks -> g in [0,65536)
    ws[2048 + g] = 0.0f;                           // zero dw
    if (g < 1024) {
        ws[1024 + g] = 0.0f;                       // zero counts
        const float* e = E + g * 64;
        // numpy pairwise_sum, n=64: 8 accumulators over strided chunks
        float r[8];
        #pragma unroll
        for (int j = 0; j < 8; ++j) r[j] = e[j] * e[j];
        #pragma unroll
        for (int t = 1; t < 8; ++t)
            #pragma unroll
            for (int j = 0; j < 8; ++j) {
                float sq = e[8 * t + j] * e[8 * t + j];
                r[j] = r[j] + sq;
            }
        ws[g] = ((r[0] + r[1]) + (r[2] + r[3])) + ((r[4] + r[5]) + (r[6] + r[7]));
    }
    if (g == 0) ws[67584] = 0.0f;                  // mse
}

// Block = 128 tokens (one row-pair of one image). 512 blocks, 256 threads.
// 8x8 register micro-tile: thread (tg,cg) owns tokens tg+16i, codes cg+16j.
__global__ __launch_bounds__(256, 2) void vq_main_kernel(
    const float* __restrict__ x, const float* __restrict__ E,
    const float* __restrict__ R, float* __restrict__ ws, float* __restrict__ out)
{
    #pragma clang fp contract(off)
    __shared__ float s_A[8704];   // x stage [64][132] -> E chunk [128][68] -> quant [128][68]
    __shared__ float s_B[8704];   // R [64][68] -> x_rot [128][68]
    __shared__ float s_ee[128];
    __shared__ float s_xx[128];
    __shared__ int   s_idx[128];
    __shared__ float s_red[8];

    const int tid = threadIdx.x;
    const int tg = tid >> 4;          // 0..15 token group  (t = tg + 16*i)
    const int cg = tid & 15;          // 0..15 code group   (c = cg + 16*j)
    const int brow = blockIdx.x;      // b*32 + hp (row-pair)
    const int b = brow >> 5, hp = brow & 31;

    const float* ee_g  = ws;
    float* counts  = ws + 1024;
    float* dw      = ws + 2048;
    float* mse_acc = ws + 67584;
    float* out_q   = out;
    float* out_idx = out + 4194305;

    const size_t xbase = (size_t)b * 262144 + (size_t)hp * 128;

    // ---- stage x tile [d][t] (stride 132) and R [d][j] (stride 68) ----
    #pragma unroll
    for (int i = 0; i < 8; ++i) {                   // x: 64 dims x 128 tokens
        int d  = i * 8 + (tid >> 5);
        int t4 = (tid & 31) * 4;
        *(float4*)&s_A[d * 132 + t4] = *(const float4*)(x + xbase + (size_t)d * 4096 + t4);
    }
    #pragma unroll
    for (int i = 0; i < 4; ++i) {                   // R: 64 x 64
        int d  = i * 16 + (tid >> 4);
        int j4 = (tid & 15) * 4;
        *(float4*)&s_B[d * 68 + j4] = *(const float4*)(R + d * 64 + j4);
    }
    __syncthreads();

    // ---- rotate: sequential-d f32 FMA chain (bit-exact); 8 tok x 4 j per thread ----
    {
        float acc[8][4] = {};
        for (int d = 0; d < 64; ++d) {
            float xv[8], rv[4];
            #pragma unroll
            for (int i = 0; i < 8; ++i) xv[i] = s_A[d * 132 + tg + 16 * i];
            #pragma unroll
            for (int jj = 0; jj < 4; ++jj) rv[jj] = s_B[d * 68 + cg + 16 * jj];
            #pragma unroll
            for (int i = 0; i < 8; ++i)
                #pragma unroll
                for (int jj = 0; jj < 4; ++jj)
                    acc[i][jj] = fmaf(xv[i], rv[jj], acc[i][jj]);
        }
        __syncthreads();              // all R reads done before overwrite
        #pragma unroll
        for (int i = 0; i < 8; ++i)
            #pragma unroll
            for (int jj = 0; jj < 4; ++jj)
                s_B[(tg + 16 * i) * 68 + cg + 16 * jj] = acc[i][jj];
    }
    __syncthreads();

    // ---- xx[t] = numpy-pairwise sum of x_rot[t][:]^2 (bit-exact np.sum order) ----
    if (tid < 128) {
        const int w = tid;
        float r[8];
        #pragma unroll
        for (int j = 0; j < 8; ++j) { float u = s_B[w * 68 + j]; r[j] = u * u; }
        #pragma unroll
        for (int t = 1; t < 8; ++t)
            #pragma unroll
            for (int j = 0; j < 8; ++j) {
                float u = s_B[w * 68 + 8 * t + j];
                float sq = u * u;
                r[j] = r[j] + sq;
            }
        s_xx[w] = ((r[0] + r[1]) + (r[2] + r[3])) + ((r[4] + r[5]) + (r[6] + r[7]));
    }
    __syncthreads();

    float xxw[8];
    #pragma unroll
    for (int i = 0; i < 8; ++i) xxw[i] = s_xx[tg + 16 * i];

    // ---- argmin of dist = fl(fl(xx+ee) - fl(2*m)), first-min tie-break ----
    float bestv[8]; int besti[8];
    #pragma unroll
    for (int i = 0; i < 8; ++i) { bestv[i] = 3.402823466e38f; besti[i] = 0; }

    for (int pc = 0; pc < 8; ++pc) {
        const int c0 = pc * 128;
        #pragma unroll
        for (int it = 0; it < 8; ++it) {            // stage 128 codes [c][d], stride 68
            int f = it * 256 + tid;
            int c = f >> 4, d4 = (f & 15) * 4;
            *(float4*)&s_A[c * 68 + d4] = *(const float4*)(E + (size_t)(c0 + c) * 64 + d4);
        }
        if (tid < 128) s_ee[tid] = ee_g[c0 + tid];
        __syncthreads();

        float acc[8][8] = {};
        #pragma unroll 4
        for (int dq = 0; dq < 16; ++dq) {
            float4 xv[8], ev[8];
            #pragma unroll
            for (int i = 0; i < 8; ++i) xv[i] = *(const float4*)&s_B[(tg + 16 * i) * 68 + dq * 4];
            #pragma unroll
            for (int j = 0; j < 8; ++j) ev[j] = *(const float4*)&s_A[(cg + 16 * j) * 68 + dq * 4];
            // k-substep interleave: per-cell chain stays dq-ascending, x->y->z->w.
            #pragma unroll
            for (int i = 0; i < 8; ++i)
                #pragma unroll
                for (int j = 0; j < 8; ++j)
                    acc[i][j] = fmaf(xv[i].x, ev[j].x, acc[i][j]);
            #pragma unroll
            for (int i = 0; i < 8; ++i)
                #pragma unroll
                for (int j = 0; j < 8; ++j)
                    acc[i][j] = fmaf(xv[i].y, ev[j].y, acc[i][j]);
            #pragma unroll
            for (int i = 0; i < 8; ++i)
                #pragma unroll
                for (int j = 0; j < 8; ++j)
                    acc[i][j] = fmaf(xv[i].z, ev[j].z, acc[i][j]);
            #pragma unroll
            for (int i = 0; i < 8; ++i)
                #pragma unroll
                for (int j = 0; j < 8; ++j)
                    acc[i][j] = fmaf(xv[i].w, ev[j].w, acc[i][j]);
        }
        #pragma unroll
        for (int j = 0; j < 8; ++j) {               // c ascending within thread
            int c = c0 + cg + 16 * j;
            float eec = s_ee[cg + 16 * j];
            #pragma unroll
            for (int i = 0; i < 8; ++i) {
                float d1 = xxw[i] + eec;            // fl(xx+ee)
                float m2 = 2.0f * acc[i][j];        // exact
                float dist = d1 - m2;               // fl(.. - ..)  (contract off)
                if (dist < bestv[i]) { bestv[i] = dist; besti[i] = c; }
            }
        }
        __syncthreads();
    }

    // ---- per-token min-reduce across the 16 code-group lanes; idx/counts/dw ----
    #pragma unroll
    for (int i = 0; i < 8; ++i) {
        float v = bestv[i]; int ix = besti[i];
        #pragma unroll
        for (int m = 1; m < 16; m <<= 1) {
            float ov = __shfl_xor(v, m, 64);
            int   oi = __shfl_xor(ix, m, 64);
            if (ov < v || (ov == v && oi < ix)) { v = ov; ix = oi; }
        }
        const int w = tg + 16 * i;
        if (cg == 0) {
            s_idx[w] = ix;
            out_idx[brow * 128 + w] = (float)ix;
            unsafeAtomicAdd(&counts[ix], 1.0f);
        }
        float4 xr = *(const float4*)&s_B[w * 68 + cg * 4];
        float* dst = dw + (size_t)ix * 64 + cg * 4;
        unsafeAtomicAdd(dst + 0, xr.x);
        unsafeAtomicAdd(dst + 1, xr.y);
        unsafeAtomicAdd(dst + 2, xr.z);
        unsafeAtomicAdd(dst + 3, xr.w);
    }
    __syncthreads();

    // ---- gather quantized rows into s_A[t][d] (stride 68) ----
    {
        int w = tid >> 1, p = (tid & 1) * 32;
        int ix = s_idx[w];
        const float* erow = E + (size_t)ix * 64 + p;
        #pragma unroll
        for (int k = 0; k < 8; ++k)
            *(float4*)&s_A[w * 68 + p + 4 * k] = *(const float4*)(erow + 4 * k);
    }
    __syncthreads();

    // ---- straight-through output + mse (token-step-1 to keep LDS conflicts low) ----
    float mse = 0.0f;
    #pragma unroll
    for (int i = 0; i < 8; ++i) {
        int d = i * 8 + (tid >> 5);
        #pragma unroll
        for (int k = 0; k < 4; ++k) {
            int t = (tid & 31) + 32 * k;
            float xv = x[xbase + (size_t)d * 4096 + t];
            float q  = s_A[t * 68 + d];
            float o  = xv + (q - xv);
            float df = q - xv;
            mse = fmaf(df, df, mse);
            out_q[xbase + (size_t)d * 4096 + t] = o;
        }
    }
    #pragma unroll
    for (int off = 32; off > 0; off >>= 1) mse += __shfl_down(mse, off, 64);
    int wave = tid >> 6, lane = tid & 63;
    if (lane == 0) s_red[wave] = mse;
    __syncthreads();
    if (tid == 0)
        unsafeAtomicAdd(mse_acc, s_red[0] + s_red[1] + s_red[2] + s_red[3]);
}

// 17 blocks x 256: blocks 0..15 -> EMA/embedding update (64 codes each);
// block 16 -> loss + new_cs. Every block self-computes n_tot (cheap).
__global__ __launch_bounds__(256) void vq_final_kernel(
    const float* __restrict__ ema_cs, const float* __restrict__ ema_w,
    const float* __restrict__ ws, float* __restrict__ out)
{
    __shared__ float s_red[8];
    __shared__ float s_inv[64];
    const int t = threadIdx.x;
    const int bid = blockIdx.x;
    const float* counts = ws + 1024;
    const float* dw     = ws + 2048;

    // ---- n_tot = sum over codes of (ema_cs*0.99 + 0.01*counts) ----
    float part = 0.0f;
    #pragma unroll
    for (int k = 0; k < 4; ++k) {
        int c = k * 256 + t;
        part += ema_cs[c] * 0.99f + 0.01f * counts[c];
    }
    #pragma unroll
    for (int off = 32; off > 0; off >>= 1) part += __shfl_down(part, off, 64);
    if ((t & 63) == 0) s_red[t >> 6] = part;
    __syncthreads();
    const float n_tot = s_red[0] + s_red[1] + s_red[2] + s_red[3];
    const float denom = n_tot + 1024.0f * 1e-5f;

    if (bid < 16) {
        const int base_code = bid * 64;
        if (t < 64) {
            int code = base_code + t;
            float ncs = ema_cs[code] * 0.99f + 0.01f * counts[code];
            float ncs_s = (ncs + 1e-5f) / denom * n_tot;
            s_inv[t] = 1.0f / ncs_s;
        }
        __syncthreads();
        float* out_emb  = out + 4259841;
        float* out_emaw = out + 4326401;
        const int base_e = base_code * 64;
        #pragma unroll
        for (int k = 0; k < 16; ++k) {
            int el = k * 256 + t;
            int e  = base_e + el;
            float nw = ema_w[e] * 0.99f + 0.01f * dw[e];
            out_emaw[e] = nw;
            out_emb[e]  = nw * s_inv[el >> 6];
        }
    } else {
        // loss + new_cs
        float ent_part = 0.0f;
        #pragma unroll
        for (int k = 0; k < 4; ++k) {
            int c = k * 256 + t;
            float cnt = counts[c];
            float p   = cnt * (1.0f / 65536.0f);
            ent_part += -p * logf(p + 1e-10f);
            float ncs = ema_cs[c] * 0.99f + 0.01f * cnt;
            out[4325377 + c] = (ncs + 1e-5f) / denom * n_tot;   // new_cs
        }
        __syncthreads();                       // s_red reuse
        #pragma unroll
        for (int off = 32; off > 0; off >>= 1) ent_part += __shfl_down(ent_part, off, 64);
        if ((t & 63) == 0) s_red[t >> 6] = ent_part;
        __syncthreads();
        if (t == 0) {
            float ent_tot = s_red[0] + s_red[1] + s_red[2] + s_red[3];
            out[4194304] = 1.25f * (ws[67584] * (1.0f / 4194304.0f)) + ent_tot;  // loss
        }
    }
}

extern "C" void kernel_launch(void* const* d_in, const int* in_sizes, int n_in,
                              void* d_out, int out_size, void* d_ws, size_t ws_size,
                              hipStream_t stream) {
    const float* x      = (const float*)d_in[0];
    const float* E      = (const float*)d_in[1];
    const float* R      = (const float*)d_in[2];
    const float* ema_cs = (const float*)d_in[3];
    const float* ema_w  = (const float*)d_in[4];
    float* out = (float*)d_out;
    float* ws  = (float*)d_ws;

    hipLaunchKernelGGL(vq_init_kernel,  dim3(256), dim3(256), 0, stream, E, ws);
    hipLaunchKernelGGL(vq_main_kernel,  dim3(512), dim3(256), 0, stream, x, E, R, ws, out);
    hipLaunchKernelGGL(vq_final_kernel, dim3(17),  dim3(256), 0, stream, ema_cs, ema_w, ws, out);
}